// Round 2
// baseline (5004.248 us; speedup 1.0000x reference)
//
#include <hip/hip_runtime.h>
#include <cstdint>
#include <cmath>
#include <vector>
#include <algorithm>
#include <numeric>

#define B_SZ 8
#define N_PTS 4096
#define TBLK 256

struct TdaArgs { int idx[16][16]; };   // rows 0..7: pred batches, 8..15: gt batches

// ---------------------------------------------------------------------------
// Kernel 1: EMD (job 0) + REP (job 1) pairwise scans.  (passed in round 1)
// ---------------------------------------------------------------------------
__global__ __launch_bounds__(TBLK)
void pair_kernel(const float* __restrict__ pred, const float* __restrict__ gt,
                 double* __restrict__ acc) {
  __shared__ float4 sg[N_PTS];         // 64 KB
  __shared__ double wred[TBLK / 64];

  const int tid   = threadIdx.x;
  const int chunk = blockIdx.x;        // 0..15
  const int b     = blockIdx.y;        // 0..7
  const int job   = blockIdx.z;        // 0 = EMD, 1 = REP

  const float* src = (job == 0 ? gt : pred) + (size_t)b * N_PTS * 3;
  for (int j = tid; j < N_PTS; j += TBLK) {
    float x = src[3 * j + 0];
    float y = src[3 * j + 1];
    float z = src[3 * j + 2];
    float nn = fmaf(x, x, fmaf(y, y, z * z));
    sg[j] = make_float4(x, y, z, -0.5f * nn);
  }
  __syncthreads();

  const int i = chunk * TBLK + tid;
  const float* pp = pred + ((size_t)b * N_PTS + i) * 3;
  const float px = pp[0], py = pp[1], pz = pp[2];
  const float pn = fmaf(px, px, fmaf(py, py, pz * pz));

  double tval;
  if (job == 0) {
    float bt = -INFINITY;
    #pragma unroll 8
    for (int j = 0; j < N_PTS; ++j) {
      float4 g = sg[j];
      float t = fmaf(px, g.x, fmaf(py, g.y, fmaf(pz, g.z, g.w)));
      bt = fmaxf(bt, t);
    }
    tval = (double)fmaf(-2.0f, bt, pn);
  } else {
    float t0 = -INFINITY, t1 = -INFINITY, t2 = -INFINITY, t3 = -INFINITY, t4 = -INFINITY;
    int   i0 = 0, i1 = 0, i2 = 0, i3 = 0, i4 = 0;
    #pragma unroll 4
    for (int j = 0; j < N_PTS; ++j) {
      float4 g = sg[j];
      float t = fmaf(px, g.x, fmaf(py, g.y, fmaf(pz, g.z, g.w)));
      if (t > t4) {
        t4 = t; i4 = j;
        if (t4 > t3) { float f = t3; t3 = t4; t4 = f; int q = i3; i3 = i4; i4 = q; }
        if (t3 > t2) { float f = t2; t2 = t3; t3 = f; int q = i2; i2 = i3; i3 = q; }
        if (t2 > t1) { float f = t1; t1 = t2; t2 = f; int q = i1; i1 = i2; i2 = q; }
        if (t1 > t0) { float f = t0; t0 = t1; t1 = f; int q = i0; i0 = i1; i1 = q; }
      }
    }
    (void)t0; (void)i0;   // rank 0 = self
    double s = 0.0;
    const int nbr[4] = { i1, i2, i3, i4 };
    #pragma unroll
    for (int k = 0; k < 4; ++k) {
      float4 g = sg[nbr[k]];
      float dx = px - g.x, dy = py - g.y, dz = pz - g.z;
      float r2 = fmaxf(fmaf(dx, dx, fmaf(dy, dy, dz * dz)), 1e-12f);
      float dist = sqrtf(r2);
      s += (double)((0.07f - dist) * expf(-r2 / 9.0e-4f));
    }
    tval = s;
  }

  double v = tval;
  #pragma unroll
  for (int off = 32; off > 0; off >>= 1) v += __shfl_down(v, off);
  if ((tid & 63) == 0) wred[tid >> 6] = v;
  __syncthreads();
  if (tid == 0) {
    double s = 0.0;
    #pragma unroll
    for (int w = 0; w < TBLK / 64; ++w) s += wred[w];
    acc[job * 128 + b * 16 + chunk] = s;
  }
}

// ---------------------------------------------------------------------------
// Kernel 2: TDA (16 serial Prim problems) + final combine.
// Distances use the reference's aa+bb-2ab formula in f32.
// ---------------------------------------------------------------------------
__global__ __launch_bounds__(64)
void final_kernel(const float* __restrict__ pred, const float* __restrict__ gt,
                  const float* __restrict__ pcd, const double* __restrict__ acc,
                  float* __restrict__ out, TdaArgs args) {
  __shared__ float pts[16][16][3];
  __shared__ float aa[16][16];
  __shared__ float mind[16][16];
  __shared__ float deaths[16][15];
  __shared__ float wd[8];
  const int tid = threadIdx.x;

  if (tid < 16) {
    const float* src = (tid < 8) ? (pred + (size_t)tid * N_PTS * 3)
                                 : (gt + (size_t)(tid - 8) * N_PTS * 3);
    for (int k = 0; k < 16; ++k) {
      int ix = args.idx[tid][k];
      float x = src[3 * ix + 0], y = src[3 * ix + 1], z = src[3 * ix + 2];
      pts[tid][k][0] = x; pts[tid][k][1] = y; pts[tid][k][2] = z;
      aa[tid][k] = x * x + y * y + z * z;
    }
    // d(j,k) = sqrt(max(aa[j] + aa[k] - 2*dot(j,k), 0))  -- reference formula
    #define DFORM(j, k) \
      sqrtf(fmaxf(aa[tid][j] + aa[tid][k] - 2.0f * (pts[tid][j][0] * pts[tid][k][0] + \
            pts[tid][j][1] * pts[tid][k][1] + pts[tid][j][2] * pts[tid][k][2]), 0.0f))
    for (int k = 0; k < 16; ++k) mind[tid][k] = DFORM(0, k);
    unsigned mask = 1u;
    for (int step = 0; step < 15; ++step) {
      float best = INFINITY; int bj = 0;
      for (int k = 0; k < 16; ++k) {
        float m = ((mask >> k) & 1u) ? INFINITY : mind[tid][k];
        if (m < best) { best = m; bj = k; }      // first-index argmin
      }
      deaths[tid][step] = best;
      mask |= (1u << bj);
      for (int k = 0; k < 16; ++k) {
        float d = DFORM(bj, k);
        mind[tid][k] = fminf(mind[tid][k], d);
      }
    }
    #undef DFORM
    for (int a = 1; a < 15; ++a) {
      float v = deaths[tid][a];
      int c = a;
      while (c > 0 && deaths[tid][c - 1] > v) { deaths[tid][c] = deaths[tid][c - 1]; --c; }
      deaths[tid][c] = v;
    }
  }
  __syncthreads();
  if (tid < 8) {
    float s = 0.0f;
    for (int k = 0; k < 15; ++k) {
      float d = deaths[tid][k] - deaths[tid + 8][k];
      s += d * d;
    }
    wd[tid] = sqrtf(s);
  }
  __syncthreads();
  if (tid == 0) {
    double tda = 0.0;
    for (int b = 0; b < 8; ++b) tda += (double)wd[b];
    tda /= 8.0;
    double emd = 0.0;
    for (int b = 0; b < 8; ++b) {
      double s = 0.0;
      for (int c = 0; c < 16; ++c) s += acc[b * 16 + c];
      emd += (s / (double)(N_PTS * 3)) / (double)pcd[b];
    }
    emd = emd / 8.0 * 100.0;
    double rep = 0.0;
    for (int k = 0; k < 128; ++k) rep += acc[128 + k];
    rep /= (double)(B_SZ * N_PTS * 4);
    out[0] = (float)emd;
    out[1] = (float)rep;
    out[2] = (float)tda;
  }
}

// ---------------------------------------------------------------------------
// Host-side JAX threefry PRNG — PARTITIONABLE convention (jax >= 0.4.30
// default: jax_threefry_partitionable=True).
//   split(key, n):  child j = (x0, x1) = threefry(key, (0, j))
//   random_bits(key, 32, (n,)): bits[i] = x0 ^ x1 of threefry(key, (0, i))
// ---------------------------------------------------------------------------
static inline uint32_t rotl32(uint32_t x, int d) { return (x << d) | (x >> (32 - d)); }

static void threefry2x32_host(uint32_t k0, uint32_t k1, uint32_t& x0, uint32_t& x1) {
  const uint32_t ks[3] = { k0, k1, k0 ^ k1 ^ 0x1BD11BDAu };
  static const int rot[2][4] = { {13, 15, 26, 6}, {17, 29, 16, 24} };
  x0 += ks[0]; x1 += ks[1];
  for (int i = 0; i < 5; ++i) {
    const int* r = rot[i & 1];
    for (int j = 0; j < 4; ++j) {
      x0 += x1;
      x1 = rotl32(x1, r[j]);
      x1 ^= x0;
    }
    x0 += ks[(i + 1) % 3];
    x1 += ks[(i + 2) % 3] + (uint32_t)(i + 1);
  }
}

static void jax_split_p(const uint32_t key[2], int n, uint32_t (*out)[2]) {
  for (int j = 0; j < n; ++j) {
    uint32_t a = 0u, b = (uint32_t)j;        // 64-bit counter j: (hi=0, lo=j)
    threefry2x32_host(key[0], key[1], a, b);
    out[j][0] = a; out[j][1] = b;
  }
}

static void jax_bits32_p(const uint32_t key[2], int n, uint32_t* bits) {
  for (int i = 0; i < n; ++i) {
    uint32_t a = 0u, b = (uint32_t)i;
    threefry2x32_host(key[0], key[1], a, b);
    bits[i] = a ^ b;                         // 32-bit output = hi ^ lo
  }
}

// jax.random.permutation(key, n)[:16] — 2 stable-sort rounds for n=4096.
static void jax_perm_first16(const uint32_t key_in[2], int n, int* out16) {
  std::vector<int> x((size_t)n);
  std::iota(x.begin(), x.end(), 0);
  uint32_t key[2] = { key_in[0], key_in[1] };
  const int rounds = (int)std::ceil(3.0 * std::log((double)n) / std::log(4294967295.0));
  std::vector<uint32_t> bits((size_t)n);
  std::vector<int> ord((size_t)n), nx((size_t)n);
  for (int r = 0; r < rounds; ++r) {
    uint32_t kr[2][2];
    jax_split_p(key, 2, kr);                 // key, subkey = split(key)
    key[0] = kr[0][0]; key[1] = kr[0][1];
    jax_bits32_p(kr[1], n, bits.data());
    std::iota(ord.begin(), ord.end(), 0);
    std::stable_sort(ord.begin(), ord.end(),
                     [&](int A, int Bv) { return bits[A] < bits[Bv]; });
    for (int i = 0; i < n; ++i) nx[i] = x[ord[i]];
    x.swap(nx);
  }
  for (int i = 0; i < 16; ++i) out16[i] = x[i];
}

static void compute_tda_indices(TdaArgs& args) {
  const uint32_t root[2] = { 0u, 42u };      // jax.random.key(42)
  uint32_t kpg[2][2];
  jax_split_p(root, 2, kpg);                 // kp, kg
  uint32_t kb[B_SZ][2];
  jax_split_p(kpg[0], B_SZ, kb);             // pred keys
  for (int b = 0; b < B_SZ; ++b) jax_perm_first16(kb[b], N_PTS, args.idx[b]);
  jax_split_p(kpg[1], B_SZ, kb);             // gt keys
  for (int b = 0; b < B_SZ; ++b) jax_perm_first16(kb[b], N_PTS, args.idx[8 + b]);
}

// ---------------------------------------------------------------------------

extern "C" void kernel_launch(void* const* d_in, const int* in_sizes, int n_in,
                              void* d_out, int out_size, void* d_ws, size_t ws_size,
                              hipStream_t stream) {
  const float* pred = (const float*)d_in[0];
  const float* gt   = (const float*)d_in[1];
  const float* pcd  = (const float*)d_in[2];
  float*  out = (float*)d_out;
  double* acc = (double*)d_ws;

  TdaArgs targs;
  compute_tda_indices(targs);

  dim3 grid(N_PTS / TBLK, B_SZ, 2);
  pair_kernel<<<grid, dim3(TBLK), 0, stream>>>(pred, gt, acc);
  final_kernel<<<dim3(1), dim3(64), 0, stream>>>(pred, gt, pcd, acc, out, targs);
}

// Round 3
// 4762.084 us; speedup vs baseline: 1.0509x; 1.0509x over previous
//
#include <hip/hip_runtime.h>
#include <cstdint>
#include <cmath>
#include <vector>
#include <algorithm>
#include <numeric>

#define B_SZ 8
#define N_PTS 4096
#define TBLK 256
#define NSPLIT 4
#define JTILE (N_PTS / NSPLIT)        // 1024 points, 16 KB LDS

struct TdaArgs { int idx[16][16]; };   // rows 0..7: pred batches, 8..15: gt batches

// ws layout (bytes):
//   bt   : [NSPLIT][8][4096] float   @ 0          (512 KB)
//   knn  : [NSPLIT][8][4096][5] int  @ 0x80000    (2.5 MB)
//   part : [128][2] double           @ 0x300000   (2 KB)
#define WS_BT(p)   ((float*)(p))
#define WS_KNN(p)  ((int*)((char*)(p) + 0x80000))
#define WS_PART(p) ((double*)((char*)(p) + 0x300000))

// ---------------------------------------------------------------------------
// Kernel 1: per-tile pairwise scans. job 0 = EMD (max t), job 1 = REP (top-5).
// t = p.g - 0.5*||g||^2 ;  argmax t == argmin dist^2.
// ---------------------------------------------------------------------------
__global__ __launch_bounds__(TBLK, 4)
void pair_kernel(const float* __restrict__ pred, const float* __restrict__ gt,
                 float* __restrict__ bt_out, int* __restrict__ knn_out) {
  __shared__ float4 sg[JTILE];         // 16 KB

  const int tid   = threadIdx.x;
  const int chunk = blockIdx.x;        // 0..15 (pred chunk)
  const int b     = blockIdx.y;        // 0..7
  const int q     = blockIdx.z % NSPLIT;   // j-tile
  const int job   = blockIdx.z / NSPLIT;   // 0 EMD, 1 REP
  const int jbase = q * JTILE;

  const float* src = (job == 0 ? gt : pred) + ((size_t)b * N_PTS + jbase) * 3;
  for (int j = tid; j < JTILE; j += TBLK) {
    float x = src[3 * j + 0];
    float y = src[3 * j + 1];
    float z = src[3 * j + 2];
    sg[j] = make_float4(x, y, z, -0.5f * fmaf(x, x, fmaf(y, y, z * z)));
  }

  const int i = chunk * TBLK + tid;
  const float* pp = pred + ((size_t)b * N_PTS + i) * 3;
  const float px = pp[0], py = pp[1], pz = pp[2];
  __syncthreads();

  if (job == 0) {
    float bt = -INFINITY;
    for (int j0 = 0; j0 < JTILE; j0 += 8) {
      float t[8];
      #pragma unroll
      for (int k = 0; k < 8; ++k) {          // 8 batched ds_read_b128
        float4 g = sg[j0 + k];
        t[k] = fmaf(px, g.x, fmaf(py, g.y, fmaf(pz, g.z, g.w)));
      }
      #pragma unroll
      for (int k = 0; k < 8; ++k) bt = fmaxf(bt, t[k]);
    }
    bt_out[((size_t)q * B_SZ + b) * N_PTS + i] = bt;
  } else {
    float t0 = -INFINITY, t1 = -INFINITY, t2 = -INFINITY, t3 = -INFINITY, t4 = -INFINITY;
    int   i0 = 0, i1 = 0, i2 = 0, i3 = 0, i4 = 0;
    for (int j0 = 0; j0 < JTILE; j0 += 8) {
      float t[8];
      #pragma unroll
      for (int k = 0; k < 8; ++k) {          // 8 batched ds_read_b128
        float4 g = sg[j0 + k];
        t[k] = fmaf(px, g.x, fmaf(py, g.y, fmaf(pz, g.z, g.w)));
      }
      float gm = fmaxf(fmaxf(fmaxf(t[0], t[1]), fmaxf(t[2], t[3])),
                       fmaxf(fmaxf(t[4], t[5]), fmaxf(t[6], t[7])));
      if (gm > t4) {                         // group-level skip (per-lane)
        #pragma unroll
        for (int k = 0; k < 8; ++k) {
          if (t[k] > t4) {                   // strict > keeps earlier index on ties
            t4 = t[k]; i4 = j0 + k;
            if (t4 > t3) { float f = t3; t3 = t4; t4 = f; int p_ = i3; i3 = i4; i4 = p_; }
            if (t3 > t2) { float f = t2; t2 = t3; t3 = f; int p_ = i2; i2 = i3; i3 = p_; }
            if (t2 > t1) { float f = t1; t1 = t2; t2 = f; int p_ = i1; i1 = i2; i2 = p_; }
            if (t1 > t0) { float f = t0; t0 = t1; t1 = f; int p_ = i0; i0 = i1; i1 = p_; }
          }
        }
      }
    }
    int* o = knn_out + (((size_t)q * B_SZ + b) * N_PTS + i) * 5;
    o[0] = jbase + i0; o[1] = jbase + i1; o[2] = jbase + i2;
    o[3] = jbase + i3; o[4] = jbase + i4;
  }
}

// ---------------------------------------------------------------------------
// Kernel 2: merge per-tile partials. One thread per (b, i).
// EMD: max over tiles -> d2 = pn - 2*bt.
// REP: exact re-rank of <=20 candidates (global gather, L2-resident), pick the
//      4 smallest (r2, idx) lexicographic excluding self, sum the rep term.
// ---------------------------------------------------------------------------
__global__ __launch_bounds__(TBLK)
void merge_kernel(const float* __restrict__ pred,
                  const float* __restrict__ bt_in, const int* __restrict__ knn_in,
                  double* __restrict__ partials) {
  __shared__ double wred[2][TBLK / 64];
  const int tid = threadIdx.x;
  const int blk = blockIdx.x;          // 0..127 ; 16 blocks per batch
  const int b   = blk >> 4;
  const int i   = (blk & 15) * TBLK + tid;

  const float* pb = pred + (size_t)b * N_PTS * 3;
  const float px = pb[3 * i + 0], py = pb[3 * i + 1], pz = pb[3 * i + 2];
  const float pn = fmaf(px, px, fmaf(py, py, pz * pz));

  // EMD
  float bt = -INFINITY;
  #pragma unroll
  for (int q = 0; q < NSPLIT; ++q)
    bt = fmaxf(bt, bt_in[((size_t)q * B_SZ + b) * N_PTS + i]);
  double emd = (double)fmaf(-2.0f, bt, pn);

  // REP: 4 smallest (r2, idx) among 4*5 candidates, self excluded
  float s0 = INFINITY, s1 = INFINITY, s2 = INFINITY, s3 = INFINITY;
  int   j0v = 0x7fffffff, j1v = 0x7fffffff, j2v = 0x7fffffff, j3v = 0x7fffffff;
  #pragma unroll
  for (int q = 0; q < NSPLIT; ++q) {
    const int* kn = knn_in + (((size_t)q * B_SZ + b) * N_PTS + i) * 5;
    #pragma unroll
    for (int c = 0; c < 5; ++c) {
      int idx = kn[c];
      float gx = pb[3 * idx + 0], gy = pb[3 * idx + 1], gz = pb[3 * idx + 2];
      float dx = px - gx, dy = py - gy, dz = pz - gz;
      float r2 = fmaf(dx, dx, fmaf(dy, dy, dz * dz));
      if (idx == i) r2 = INFINITY;                    // drop self
      bool lt3 = (r2 < s3) || (r2 == s3 && idx < j3v);
      if (lt3) {
        s3 = r2; j3v = idx;
        if ((s3 < s2) || (s3 == s2 && j3v < j2v)) { float f = s2; s2 = s3; s3 = f; int p_ = j2v; j2v = j3v; j3v = p_; }
        if ((s2 < s1) || (s2 == s1 && j2v < j1v)) { float f = s1; s1 = s2; s2 = f; int p_ = j1v; j1v = j2v; j2v = p_; }
        if ((s1 < s0) || (s1 == s0 && j1v < j0v)) { float f = s0; s0 = s1; s1 = f; int p_ = j0v; j0v = j1v; j1v = p_; }
      }
    }
  }
  double rep = 0.0;
  {
    float rr[4] = { s0, s1, s2, s3 };
    #pragma unroll
    for (int k = 0; k < 4; ++k) {
      float r2 = fmaxf(rr[k], 1e-12f);
      float dist = sqrtf(r2);
      rep += (double)((0.07f - dist) * expf(-r2 / 9.0e-4f));
    }
  }

  // deterministic block reduction
  double v0 = emd, v1 = rep;
  #pragma unroll
  for (int off = 32; off > 0; off >>= 1) { v0 += __shfl_down(v0, off); v1 += __shfl_down(v1, off); }
  if ((tid & 63) == 0) { wred[0][tid >> 6] = v0; wred[1][tid >> 6] = v1; }
  __syncthreads();
  if (tid == 0) {
    double a = 0.0, r = 0.0;
    #pragma unroll
    for (int w = 0; w < TBLK / 64; ++w) { a += wred[0][w]; r += wred[1][w]; }
    partials[blk * 2 + 0] = a;
    partials[blk * 2 + 1] = r;
  }
}

// ---------------------------------------------------------------------------
// Kernel 3: TDA (16 serial Prim problems) + final combine.
// ---------------------------------------------------------------------------
__global__ __launch_bounds__(64)
void final_kernel(const float* __restrict__ pred, const float* __restrict__ gt,
                  const float* __restrict__ pcd, const double* __restrict__ partials,
                  float* __restrict__ out, TdaArgs args) {
  __shared__ float pts[16][16][3];
  __shared__ float aa[16][16];
  __shared__ float mind[16][16];
  __shared__ float deaths[16][15];
  __shared__ float wd[8];
  const int tid = threadIdx.x;

  if (tid < 16) {
    const float* src = (tid < 8) ? (pred + (size_t)tid * N_PTS * 3)
                                 : (gt + (size_t)(tid - 8) * N_PTS * 3);
    for (int k = 0; k < 16; ++k) {
      int ix = args.idx[tid][k];
      float x = src[3 * ix + 0], y = src[3 * ix + 1], z = src[3 * ix + 2];
      pts[tid][k][0] = x; pts[tid][k][1] = y; pts[tid][k][2] = z;
      aa[tid][k] = x * x + y * y + z * z;
    }
    #define DFORM(j, k) \
      sqrtf(fmaxf(aa[tid][j] + aa[tid][k] - 2.0f * (pts[tid][j][0] * pts[tid][k][0] + \
            pts[tid][j][1] * pts[tid][k][1] + pts[tid][j][2] * pts[tid][k][2]), 0.0f))
    for (int k = 0; k < 16; ++k) mind[tid][k] = DFORM(0, k);
    unsigned mask = 1u;
    for (int step = 0; step < 15; ++step) {
      float best = INFINITY; int bj = 0;
      for (int k = 0; k < 16; ++k) {
        float m = ((mask >> k) & 1u) ? INFINITY : mind[tid][k];
        if (m < best) { best = m; bj = k; }      // first-index argmin
      }
      deaths[tid][step] = best;
      mask |= (1u << bj);
      for (int k = 0; k < 16; ++k) mind[tid][k] = fminf(mind[tid][k], DFORM(bj, k));
    }
    #undef DFORM
    for (int a = 1; a < 15; ++a) {
      float v = deaths[tid][a];
      int c = a;
      while (c > 0 && deaths[tid][c - 1] > v) { deaths[tid][c] = deaths[tid][c - 1]; --c; }
      deaths[tid][c] = v;
    }
  }
  __syncthreads();
  if (tid < 8) {
    float s = 0.0f;
    for (int k = 0; k < 15; ++k) {
      float d = deaths[tid][k] - deaths[tid + 8][k];
      s += d * d;
    }
    wd[tid] = sqrtf(s);
  }
  __syncthreads();
  if (tid == 0) {
    double tda = 0.0;
    for (int b = 0; b < 8; ++b) tda += (double)wd[b];
    tda /= 8.0;
    double emd = 0.0;
    for (int b = 0; b < 8; ++b) {
      double s = 0.0;
      for (int c = 0; c < 16; ++c) s += partials[(b * 16 + c) * 2];
      emd += (s / (double)(N_PTS * 3)) / (double)pcd[b];
    }
    emd = emd / 8.0 * 100.0;
    double rep = 0.0;
    for (int k = 0; k < 128; ++k) rep += partials[k * 2 + 1];
    rep /= (double)(B_SZ * N_PTS * 4);
    out[0] = (float)emd;
    out[1] = (float)rep;
    out[2] = (float)tda;
  }
}

// ---------------------------------------------------------------------------
// Host-side JAX threefry PRNG — partitionable convention (verified round 2).
// ---------------------------------------------------------------------------
static inline uint32_t rotl32(uint32_t x, int d) { return (x << d) | (x >> (32 - d)); }

static void threefry2x32_host(uint32_t k0, uint32_t k1, uint32_t& x0, uint32_t& x1) {
  const uint32_t ks[3] = { k0, k1, k0 ^ k1 ^ 0x1BD11BDAu };
  static const int rot[2][4] = { {13, 15, 26, 6}, {17, 29, 16, 24} };
  x0 += ks[0]; x1 += ks[1];
  for (int i = 0; i < 5; ++i) {
    const int* r = rot[i & 1];
    for (int j = 0; j < 4; ++j) {
      x0 += x1;
      x1 = rotl32(x1, r[j]);
      x1 ^= x0;
    }
    x0 += ks[(i + 1) % 3];
    x1 += ks[(i + 2) % 3] + (uint32_t)(i + 1);
  }
}

static void jax_split_p(const uint32_t key[2], int n, uint32_t (*out)[2]) {
  for (int j = 0; j < n; ++j) {
    uint32_t a = 0u, b = (uint32_t)j;
    threefry2x32_host(key[0], key[1], a, b);
    out[j][0] = a; out[j][1] = b;
  }
}

static void jax_bits32_p(const uint32_t key[2], int n, uint32_t* bits) {
  for (int i = 0; i < n; ++i) {
    uint32_t a = 0u, b = (uint32_t)i;
    threefry2x32_host(key[0], key[1], a, b);
    bits[i] = a ^ b;
  }
}

static void jax_perm_first16(const uint32_t key_in[2], int n, int* out16) {
  std::vector<int> x((size_t)n);
  std::iota(x.begin(), x.end(), 0);
  uint32_t key[2] = { key_in[0], key_in[1] };
  const int rounds = (int)std::ceil(3.0 * std::log((double)n) / std::log(4294967295.0));
  std::vector<uint32_t> bits((size_t)n);
  std::vector<int> ord((size_t)n), nx((size_t)n);
  for (int r = 0; r < rounds; ++r) {
    uint32_t kr[2][2];
    jax_split_p(key, 2, kr);
    key[0] = kr[0][0]; key[1] = kr[0][1];
    jax_bits32_p(kr[1], n, bits.data());
    std::iota(ord.begin(), ord.end(), 0);
    std::stable_sort(ord.begin(), ord.end(),
                     [&](int A, int Bv) { return bits[A] < bits[Bv]; });
    for (int i = 0; i < n; ++i) nx[i] = x[ord[i]];
    x.swap(nx);
  }
  for (int i = 0; i < 16; ++i) out16[i] = x[i];
}

static void compute_tda_indices(TdaArgs& args) {
  const uint32_t root[2] = { 0u, 42u };
  uint32_t kpg[2][2];
  jax_split_p(root, 2, kpg);
  uint32_t kb[B_SZ][2];
  jax_split_p(kpg[0], B_SZ, kb);
  for (int b = 0; b < B_SZ; ++b) jax_perm_first16(kb[b], N_PTS, args.idx[b]);
  jax_split_p(kpg[1], B_SZ, kb);
  for (int b = 0; b < B_SZ; ++b) jax_perm_first16(kb[b], N_PTS, args.idx[8 + b]);
}

// ---------------------------------------------------------------------------

extern "C" void kernel_launch(void* const* d_in, const int* in_sizes, int n_in,
                              void* d_out, int out_size, void* d_ws, size_t ws_size,
                              hipStream_t stream) {
  const float* pred = (const float*)d_in[0];
  const float* gt   = (const float*)d_in[1];
  const float* pcd  = (const float*)d_in[2];
  float* out = (float*)d_out;

  TdaArgs targs;
  compute_tda_indices(targs);

  float*  bt   = WS_BT(d_ws);
  int*    knn  = WS_KNN(d_ws);
  double* part = WS_PART(d_ws);

  pair_kernel<<<dim3(N_PTS / TBLK, B_SZ, 2 * NSPLIT), dim3(TBLK), 0, stream>>>(pred, gt, bt, knn);
  merge_kernel<<<dim3(B_SZ * N_PTS / TBLK), dim3(TBLK), 0, stream>>>(pred, bt, knn, part);
  final_kernel<<<dim3(1), dim3(64), 0, stream>>>(pred, gt, pcd, part, out, targs);
}